// Round 1
// baseline (382.445 us; speedup 1.0000x reference)
//
#include <hip/hip_runtime.h>
#include <math.h>

// Decoder: h = relu(cat @ W_h + b_h); t = selu(h @ W1 + b1);
// x = sigmoid(t @ W2 + b2); loss = -(log(x+e)*img + log(1-x+e)*(1-img)).sum(w)
// Shapes: S=8 B=512 -> R=4096 rows; Hn=512, bott=160, P=12288=192 groups * 64.

#define SELU_SCALE 1.0507009873554804934193349852946f
#define SELU_ALPHA 1.6732632423543772848170429916717f
#define EPS 1e-9f

// ---------------- K1: h[R,512] = relu(concat(digits,styles) @ Wh + bh) -----
// block = 512 threads (one per output column), 8 rows per block.
__global__ __launch_bounds__(512) void dec_hidden_kernel(
    const float* __restrict__ digits,   // [R,10]
    const float* __restrict__ styles,   // [R,50]
    const float* __restrict__ Wh,       // [60,512]
    const float* __restrict__ bh,       // [512]
    float* __restrict__ h)              // [R,512]
{
    __shared__ float cat_s[8][60];
    const int tid = threadIdx.x;
    const int rowBase = blockIdx.x * 8;

    for (int i = tid; i < 8 * 60; i += 512) {
        const int r = i / 60, k = i % 60;
        const int row = rowBase + r;
        cat_s[r][k] = (k < 10) ? digits[row * 10 + k]
                               : styles[row * 50 + (k - 10)];
    }
    __syncthreads();

    float acc[8];
    const float bias = bh[tid];
#pragma unroll
    for (int r = 0; r < 8; ++r) acc[r] = bias;

    for (int k = 0; k < 60; ++k) {
        const float w = Wh[k * 512 + tid];
#pragma unroll
        for (int r = 0; r < 8; ++r) acc[r] += cat_s[r][k] * w;
    }
#pragma unroll
    for (int r = 0; r < 8; ++r)
        h[(size_t)(rowBase + r) * 512 + tid] = fmaxf(acc[r], 0.0f);
}

// ---------------- K2: t[R,160] = selu(h @ W1 + b1) -------------------------
// block = 192 threads (160 active own a column), 8 rows per block.
__global__ __launch_bounds__(192) void hidden1_kernel(
    const float* __restrict__ h,    // [R,512]
    const float* __restrict__ W1,   // [512,160]
    const float* __restrict__ b1,   // [160]
    float* __restrict__ t)          // [R,160]
{
    __shared__ float h_s[8 * 512];
    const int tid = threadIdx.x;
    const int rowBase = blockIdx.x * 8;
    const float* hsrc = h + (size_t)rowBase * 512;  // tile is contiguous
    for (int i = tid; i < 8 * 512; i += 192) h_s[i] = hsrc[i];
    __syncthreads();

    if (tid < 160) {
        float acc[8];
        const float bias = b1[tid];
#pragma unroll
        for (int r = 0; r < 8; ++r) acc[r] = bias;

        for (int k = 0; k < 512; ++k) {
            const float w = W1[k * 160 + tid];
#pragma unroll
            for (int r = 0; r < 8; ++r) acc[r] += h_s[r * 512 + k] * w;
        }
#pragma unroll
        for (int r = 0; r < 8; ++r) {
            const float z = acc[r];
            const float s = (z > 0.0f) ? (SELU_SCALE * z)
                                       : (SELU_SCALE * SELU_ALPHA * expm1f(z));
            t[(size_t)(rowBase + r) * 160 + tid] = s;
        }
    }
}

// ---------------- K3: fused x=sigmoid(t@W2+b2) + BCE loss reduce over w ----
// grid = (192 col-groups, 64 row-tiles); block = 256 = 16x16 threads.
// Tile: 64 rows x 64 cols (= exactly one (c,h) output group of w=64).
// Each thread: 4 rows x 4 cols micro-tile; t-tile in LDS (stride 161 pad).
__global__ __launch_bounds__(256) void out_loss_kernel(
    const float* __restrict__ t,       // [R,160]
    const float* __restrict__ W2,      // [160,12288]
    const float* __restrict__ b2,      // [12288]
    const float* __restrict__ images,  // [R,12288]
    float* __restrict__ out)           // [R,192]
{
    __shared__ float ts[64][161];  // padded: row offsets 644 % 32 != 0
    const int tid = threadIdx.x;
    const int rowBase = blockIdx.y * 64;
    const int colBase = blockIdx.x * 64;

    // stage t tile (rows contiguous -> one linear copy)
    {
        const float* tsrc = t + (size_t)rowBase * 160;
        for (int i = tid; i < 64 * 160; i += 256)
            ts[i / 160][i % 160] = tsrc[i];
    }
    __syncthreads();

    const int tx = tid & 15;   // col group (4 cols each)
    const int ty = tid >> 4;   // row group (4 rows each)

    float acc[4][4] = {{0.f}};
    const float* w2p = W2 + colBase + (tx << 2);

#pragma unroll 4
    for (int k = 0; k < 160; ++k) {
        const float4 b = *(const float4*)(w2p + (size_t)k * 12288);
#pragma unroll
        for (int r = 0; r < 4; ++r) {
            const float a = ts[(ty << 2) + r][k];
            acc[r][0] = fmaf(a, b.x, acc[r][0]);
            acc[r][1] = fmaf(a, b.y, acc[r][1]);
            acc[r][2] = fmaf(a, b.z, acc[r][2]);
            acc[r][3] = fmaf(a, b.w, acc[r][3]);
        }
    }

    // epilogue: bias -> sigmoid -> BCE terms vs images, partial per row
    const float4 bias4 = *(const float4*)(b2 + colBase + (tx << 2));
    const float bc[4] = {bias4.x, bias4.y, bias4.z, bias4.w};

    float part[4];
#pragma unroll
    for (int r = 0; r < 4; ++r) {
        const int row = rowBase + (ty << 2) + r;
        const float4 img4 =
            *(const float4*)(images + (size_t)row * 12288 + colBase + (tx << 2));
        const float im[4] = {img4.x, img4.y, img4.z, img4.w};
        float p = 0.0f;
#pragma unroll
        for (int c = 0; c < 4; ++c) {
            const float z = acc[r][c] + bc[c];
            const float x = 1.0f / (1.0f + expf(-z));
            p += logf(x + EPS) * im[c] + logf(1.0f - x + EPS) * (1.0f - im[c]);
        }
        part[r] = p;
    }

    // reduce across the 16 tx lanes (w dimension), groups of 16 within wave
#pragma unroll
    for (int off = 8; off >= 1; off >>= 1) {
#pragma unroll
        for (int r = 0; r < 4; ++r)
            part[r] += __shfl_xor(part[r], off, 16);
    }

    if (tx == 0) {
#pragma unroll
        for (int r = 0; r < 4; ++r) {
            const int row = rowBase + (ty << 2) + r;
            out[(size_t)row * 192 + blockIdx.x] = -part[r];
        }
    }
}

extern "C" void kernel_launch(void* const* d_in, const int* in_sizes, int n_in,
                              void* d_out, int out_size, void* d_ws, size_t ws_size,
                              hipStream_t stream) {
    const float* digits = (const float*)d_in[0];  // [8,512,10]
    const float* styles = (const float*)d_in[1];  // [8,512,50]
    const float* images = (const float*)d_in[2];  // [8,512,3,64,64]
    const float* Wh     = (const float*)d_in[3];  // [60,512]
    const float* bh     = (const float*)d_in[4];  // [512]
    const float* W1     = (const float*)d_in[5];  // [512,160]
    const float* b1     = (const float*)d_in[6];  // [160]
    const float* W2     = (const float*)d_in[7];  // [160,12288]
    const float* b2     = (const float*)d_in[8];  // [12288]
    float* out = (float*)d_out;                   // [8,512,3,64] = [4096,192]

    const int R = 4096;

    // workspace: h [R,512] then t [R,160]
    float* h = (float*)d_ws;
    float* t = h + (size_t)R * 512;

    dec_hidden_kernel<<<R / 8, 512, 0, stream>>>(digits, styles, Wh, bh, h);
    hidden1_kernel<<<R / 8, 192, 0, stream>>>(h, W1, b1, t);

    dim3 grid3(192, R / 64);
    out_loss_kernel<<<grid3, 256, 0, stream>>>(t, W2, b2, images, out);
}

// Round 2
// 203.754 us; speedup vs baseline: 1.8770x; 1.8770x over previous
//
#include <hip/hip_runtime.h>
#include <hip/hip_bf16.h>
#include <math.h>

// Decoder: h = relu(cat @ W_h + b_h); t = selu(h @ W1 + b1);
// x = sigmoid(t @ W2 + b2); loss = sum_w(softplus(z) - z*img)   [== -(BCE log-lik)]
// R = S*B = 4096 rows; Hn=512, bott=160, P=12288 = 192 groups * 64 (w).

#define SELU_SCALE 1.0507009873554804934193349852946f
#define SELU_ALPHA 1.6732632423543772848170429916717f

typedef __attribute__((ext_vector_type(8))) short bf16x8;   // 8 bf16 (4 VGPRs)
typedef __attribute__((ext_vector_type(4))) float f32x4;    // MFMA accumulator

// ---------------- K0: W2T[n][k] = bf16(W2[k][n]) ---------------------------
// grid (384, 5), block 256; 32x32 tiles, LDS transpose with +1 pad.
__global__ __launch_bounds__(256) void w2_transpose_kernel(
    const float* __restrict__ W2,        // [160,12288]
    __hip_bfloat16* __restrict__ W2T)    // [12288,160]
{
    __shared__ float tile[32][33];
    const int nBase = blockIdx.x * 32;
    const int kBase = blockIdx.y * 32;
    const int tx = threadIdx.x & 31;
    const int ty = threadIdx.x >> 5;     // 0..7
#pragma unroll
    for (int i = 0; i < 4; ++i) {
        const int k = kBase + ty + i * 8;
        tile[ty + i * 8][tx] = W2[(size_t)k * 12288 + nBase + tx];
    }
    __syncthreads();
#pragma unroll
    for (int i = 0; i < 4; ++i) {
        const int n = nBase + ty + i * 8;
        W2T[(size_t)n * 160 + kBase + tx] = __float2bfloat16(tile[tx][ty + i * 8]);
    }
}

// ---------------- K1: h[R,512] = bf16(relu(cat @ Wh + bh)) -----------------
__global__ __launch_bounds__(512) void dec_hidden_kernel(
    const float* __restrict__ digits,   // [R,10]
    const float* __restrict__ styles,   // [R,50]
    const float* __restrict__ Wh,       // [60,512]
    const float* __restrict__ bh,       // [512]
    __hip_bfloat16* __restrict__ h)     // [R,512] bf16
{
    __shared__ float cat_s[8][60];
    const int tid = threadIdx.x;
    const int rowBase = blockIdx.x * 8;

    for (int i = tid; i < 8 * 60; i += 512) {
        const int r = i / 60, k = i % 60;
        const int row = rowBase + r;
        cat_s[r][k] = (k < 10) ? digits[row * 10 + k]
                               : styles[row * 50 + (k - 10)];
    }
    __syncthreads();

    float acc[8];
    const float bias = bh[tid];
#pragma unroll
    for (int r = 0; r < 8; ++r) acc[r] = bias;

    for (int k = 0; k < 60; ++k) {
        const float w = Wh[k * 512 + tid];
#pragma unroll
        for (int r = 0; r < 8; ++r) acc[r] = fmaf(cat_s[r][k], w, acc[r]);
    }
#pragma unroll
    for (int r = 0; r < 8; ++r)
        h[(size_t)(rowBase + r) * 512 + tid] = __float2bfloat16(fmaxf(acc[r], 0.0f));
}

// ---------------- K2: t[R,160] = bf16(selu(h @ W1 + b1)) -------------------
// block = 192 threads (160 active), 8 rows per block; k vectorized by 4.
__global__ __launch_bounds__(192) void hidden1_kernel(
    const __hip_bfloat16* __restrict__ h,   // [R,512] bf16
    const float* __restrict__ W1,           // [512,160]
    const float* __restrict__ b1,           // [160]
    __hip_bfloat16* __restrict__ t)         // [R,160] bf16
{
    __shared__ float h_s[8 * 512];
    const int tid = threadIdx.x;
    const int rowBase = blockIdx.x * 8;
    const __hip_bfloat16* hsrc = h + (size_t)rowBase * 512;
    for (int i = tid; i < 8 * 512; i += 192) h_s[i] = __bfloat162float(hsrc[i]);
    __syncthreads();

    if (tid < 160) {
        float acc[8];
        const float bias = b1[tid];
#pragma unroll
        for (int r = 0; r < 8; ++r) acc[r] = bias;

        for (int k = 0; k < 512; k += 4) {
            const float w0 = W1[(size_t)(k + 0) * 160 + tid];
            const float w1 = W1[(size_t)(k + 1) * 160 + tid];
            const float w2 = W1[(size_t)(k + 2) * 160 + tid];
            const float w3 = W1[(size_t)(k + 3) * 160 + tid];
#pragma unroll
            for (int r = 0; r < 8; ++r) {
                const float4 hv = *(const float4*)&h_s[r * 512 + k];
                float a = acc[r];
                a = fmaf(hv.x, w0, a);
                a = fmaf(hv.y, w1, a);
                a = fmaf(hv.z, w2, a);
                a = fmaf(hv.w, w3, a);
                acc[r] = a;
            }
        }
#pragma unroll
        for (int r = 0; r < 8; ++r) {
            const float z = acc[r];
            const float s = (z > 0.0f) ? (SELU_SCALE * z)
                                       : (SELU_SCALE * SELU_ALPHA * expm1f(z));
            t[(size_t)(rowBase + r) * 160 + tid] = __float2bfloat16(s);
        }
    }
}

// ---------------- K3: MFMA GEMM (t @ W2) fused with sigmoid-BCE loss -------
// grid (96, 32); block 256 = 4 waves as 2x2; block tile 128x128, wave 64x64.
// A = t[4096,160] bf16 row-major; B = W2T[12288,160] bf16 row-major (=W2^T).
// No LDS: fragments are direct 16B/lane global loads (L2-resident operands).
__global__ __launch_bounds__(256) void out_loss_mfma_kernel(
    const __hip_bfloat16* __restrict__ t,    // [4096,160]
    const __hip_bfloat16* __restrict__ w2t,  // [12288,160]
    const float* __restrict__ b2,            // [12288]
    const float* __restrict__ images,        // [4096,12288]
    float* __restrict__ out)                 // [4096,192]
{
    const int tid = threadIdx.x;
    const int lane = tid & 63;
    const int wv = tid >> 6;
    const int wm = wv >> 1, wn = wv & 1;
    const int rowBase = blockIdx.y * 128 + wm * 64;
    const int colBase = blockIdx.x * 128 + wn * 64;
    const int lr = lane & 15;     // 16-dim index within fragment
    const int lh = lane >> 4;     // k-block / row-group index

    const short* tb = (const short*)t;
    const short* wb = (const short*)w2t;

    f32x4 acc[4][4] = {};

#pragma unroll
    for (int kk = 0; kk < 5; ++kk) {          // K = 160 = 5 * 32
        bf16x8 a[4], b[4];
#pragma unroll
        for (int m = 0; m < 4; ++m)
            a[m] = *(const bf16x8*)(tb + (size_t)(rowBase + m * 16 + lr) * 160
                                       + kk * 32 + lh * 8);
#pragma unroll
        for (int n = 0; n < 4; ++n)
            b[n] = *(const bf16x8*)(wb + (size_t)(colBase + n * 16 + lr) * 160
                                       + kk * 32 + lh * 8);
#pragma unroll
        for (int m = 0; m < 4; ++m)
#pragma unroll
            for (int n = 0; n < 4; ++n)
                acc[m][n] = __builtin_amdgcn_mfma_f32_16x16x32_bf16(
                    a[m], b[n], acc[m][n], 0, 0, 0);
    }

    // Epilogue: z = acc + b2; loss terms softplus(z) - z*img; reduce over w=64.
    // C/D layout: col = lane&15, row = (lane>>4)*4 + j   [m89-verified]
    const int group = blockIdx.x * 2 + wn;    // w-group = 64-col slab
#pragma unroll
    for (int m = 0; m < 4; ++m) {
        float part[4] = {0.f, 0.f, 0.f, 0.f};
#pragma unroll
        for (int n = 0; n < 4; ++n) {
            const int col = colBase + n * 16 + lr;
            const float bias = b2[col];
#pragma unroll
            for (int j = 0; j < 4; ++j) {
                const int row = rowBase + m * 16 + lh * 4 + j;
                const float z = acc[m][n][j] + bias;
                const float im = images[(size_t)row * 12288 + col];
                const float sp = fmaxf(z, 0.0f) + log1pf(expf(-fabsf(z)));
                part[j] += sp - z * im;
            }
        }
#pragma unroll
        for (int off = 8; off >= 1; off >>= 1)
#pragma unroll
            for (int j = 0; j < 4; ++j)
                part[j] += __shfl_xor(part[j], off, 16);
        if (lr == 0) {
#pragma unroll
            for (int j = 0; j < 4; ++j)
                out[(size_t)(rowBase + m * 16 + lh * 4 + j) * 192 + group] = part[j];
        }
    }
}

extern "C" void kernel_launch(void* const* d_in, const int* in_sizes, int n_in,
                              void* d_out, int out_size, void* d_ws, size_t ws_size,
                              hipStream_t stream) {
    const float* digits = (const float*)d_in[0];  // [8,512,10]
    const float* styles = (const float*)d_in[1];  // [8,512,50]
    const float* images = (const float*)d_in[2];  // [8,512,3,64,64]
    const float* Wh     = (const float*)d_in[3];  // [60,512]
    const float* bh     = (const float*)d_in[4];  // [512]
    const float* W1     = (const float*)d_in[5];  // [512,160]
    const float* b1     = (const float*)d_in[6];  // [160]
    const float* W2     = (const float*)d_in[7];  // [160,12288]
    const float* b2     = (const float*)d_in[8];  // [12288]
    float* out = (float*)d_out;                   // [4096,192]

    const int R = 4096;

    // workspace (9 MB total): h bf16 [R,512] | t bf16 [R,160] | W2T bf16 [12288,160]
    __hip_bfloat16* h   = (__hip_bfloat16*)d_ws;
    __hip_bfloat16* tt  = h + (size_t)R * 512;
    __hip_bfloat16* w2t = tt + (size_t)R * 160;

    dim3 gridT(384, 5);
    w2_transpose_kernel<<<gridT, 256, 0, stream>>>(W2, w2t);

    dec_hidden_kernel<<<R / 8, 512, 0, stream>>>(digits, styles, Wh, bh, h);
    hidden1_kernel<<<R / 8, 192, 0, stream>>>(h, W1, b1, tt);

    dim3 grid3(96, 32);
    out_loss_mfma_kernel<<<grid3, 256, 0, stream>>>(tt, w2t, b2, images, out);
}

// Round 3
// 113.468 us; speedup vs baseline: 3.3705x; 1.7957x over previous
//
#include <hip/hip_runtime.h>
#include <hip/hip_bf16.h>
#include <math.h>

// Decoder: h = relu(cat @ W_h + b_h); t = selu(h @ W1 + b1);
// x = sigmoid(t @ W2 + b2); loss = sum_w(softplus(z) - z*img)   [== -(BCE log-lik)]
// R = S*B = 4096 rows; Hn=512, bott=160, P=12288 = 192 groups * 64 (w).

#define SELU_SCALE 1.0507009873554804934193349852946f
#define SELU_ALPHA 1.6732632423543772848170429916717f

typedef __attribute__((ext_vector_type(8))) short bf16x8;   // 8 bf16 (4 VGPRs)
typedef __attribute__((ext_vector_type(4))) float f32x4;    // MFMA accumulator

// ---------------- K0: W2T[n][k] = bf16(W2[k][n]) ---------------------------
__global__ __launch_bounds__(256) void w2_transpose_kernel(
    const float* __restrict__ W2,        // [160,12288]
    __hip_bfloat16* __restrict__ W2T)    // [12288,160]
{
    __shared__ float tile[32][33];
    const int nBase = blockIdx.x * 32;
    const int kBase = blockIdx.y * 32;
    const int tx = threadIdx.x & 31;
    const int ty = threadIdx.x >> 5;     // 0..7
#pragma unroll
    for (int i = 0; i < 4; ++i) {
        const int k = kBase + ty + i * 8;
        tile[ty + i * 8][tx] = W2[(size_t)k * 12288 + nBase + tx];
    }
    __syncthreads();
#pragma unroll
    for (int i = 0; i < 4; ++i) {
        const int n = nBase + ty + i * 8;
        W2T[(size_t)n * 160 + kBase + tx] = __float2bfloat16(tile[tx][ty + i * 8]);
    }
}

// ---------------- K1: h[R,512] = bf16(relu(cat @ Wh + bh)) -----------------
__global__ __launch_bounds__(512) void dec_hidden_kernel(
    const float* __restrict__ digits,   // [R,10]
    const float* __restrict__ styles,   // [R,50]
    const float* __restrict__ Wh,       // [60,512]
    const float* __restrict__ bh,       // [512]
    __hip_bfloat16* __restrict__ h)     // [R,512] bf16
{
    __shared__ float cat_s[8][60];
    const int tid = threadIdx.x;
    const int rowBase = blockIdx.x * 8;

    for (int i = tid; i < 8 * 60; i += 512) {
        const int r = i / 60, k = i % 60;
        const int row = rowBase + r;
        cat_s[r][k] = (k < 10) ? digits[row * 10 + k]
                               : styles[row * 50 + (k - 10)];
    }
    __syncthreads();

    float acc[8];
    const float bias = bh[tid];
#pragma unroll
    for (int r = 0; r < 8; ++r) acc[r] = bias;

    for (int k = 0; k < 60; ++k) {
        const float w = Wh[k * 512 + tid];
#pragma unroll
        for (int r = 0; r < 8; ++r) acc[r] = fmaf(cat_s[r][k], w, acc[r]);
    }
#pragma unroll
    for (int r = 0; r < 8; ++r)
        h[(size_t)(rowBase + r) * 512 + tid] = __float2bfloat16(fmaxf(acc[r], 0.0f));
}

// ---------------- K2: t[R,160] = bf16(selu(h @ W1 + b1)) -------------------
__global__ __launch_bounds__(192) void hidden1_kernel(
    const __hip_bfloat16* __restrict__ h,   // [R,512] bf16
    const float* __restrict__ W1,           // [512,160]
    const float* __restrict__ b1,           // [160]
    __hip_bfloat16* __restrict__ t)         // [R,160] bf16
{
    __shared__ float h_s[8 * 512];
    const int tid = threadIdx.x;
    const int rowBase = blockIdx.x * 8;
    const __hip_bfloat16* hsrc = h + (size_t)rowBase * 512;
    for (int i = tid; i < 8 * 512; i += 192) h_s[i] = __bfloat162float(hsrc[i]);
    __syncthreads();

    if (tid < 160) {
        float acc[8];
        const float bias = b1[tid];
#pragma unroll
        for (int r = 0; r < 8; ++r) acc[r] = bias;

        for (int k = 0; k < 512; k += 4) {
            const float w0 = W1[(size_t)(k + 0) * 160 + tid];
            const float w1 = W1[(size_t)(k + 1) * 160 + tid];
            const float w2 = W1[(size_t)(k + 2) * 160 + tid];
            const float w3 = W1[(size_t)(k + 3) * 160 + tid];
#pragma unroll
            for (int r = 0; r < 8; ++r) {
                const float4 hv = *(const float4*)&h_s[r * 512 + k];
                float a = acc[r];
                a = fmaf(hv.x, w0, a);
                a = fmaf(hv.y, w1, a);
                a = fmaf(hv.z, w2, a);
                a = fmaf(hv.w, w3, a);
                acc[r] = a;
            }
        }
#pragma unroll
        for (int r = 0; r < 8; ++r) {
            const float z = acc[r];
            const float s = (z > 0.0f) ? (SELU_SCALE * z)
                                       : (SELU_SCALE * SELU_ALPHA * expm1f(z));
            t[(size_t)(rowBase + r) * 160 + tid] = __float2bfloat16(s);
        }
    }
}

// ---------------- K3: MFMA GEMM (t @ W2) fused with sigmoid-BCE loss -------
// grid (96, 32); block 256 = 4 waves as 2x2; block tile 128x128, wave 64x64.
// Epilogue math: loss_elem = softplus(z) - z*img, softplus via NATIVE
// v_exp_f32/v_log_f32; Σ_n log(1+e_n) folded to log(Π_n(1+e_n)) — one
// v_log_f32 per 4 elements. Product ∈ (1,16], fp32-safe.
__global__ __launch_bounds__(256) void out_loss_mfma_kernel(
    const __hip_bfloat16* __restrict__ t,    // [4096,160]
    const __hip_bfloat16* __restrict__ w2t,  // [12288,160]
    const float* __restrict__ b2,            // [12288]
    const float* __restrict__ images,        // [4096,12288]
    float* __restrict__ out)                 // [4096,192]
{
    const int tid = threadIdx.x;
    const int lane = tid & 63;
    const int wv = tid >> 6;
    const int wm = wv >> 1, wn = wv & 1;
    const int rowBase = blockIdx.y * 128 + wm * 64;
    const int colBase = blockIdx.x * 128 + wn * 64;
    const int lr = lane & 15;     // 16-dim index within fragment
    const int lh = lane >> 4;     // k-block / row-group index

    const short* tb = (const short*)t;
    const short* wb = (const short*)w2t;

    f32x4 acc[4][4] = {};

#pragma unroll
    for (int kk = 0; kk < 5; ++kk) {          // K = 160 = 5 * 32
        bf16x8 a[4], b[4];
#pragma unroll
        for (int m = 0; m < 4; ++m)
            a[m] = *(const bf16x8*)(tb + (size_t)(rowBase + m * 16 + lr) * 160
                                       + kk * 32 + lh * 8);
#pragma unroll
        for (int n = 0; n < 4; ++n)
            b[n] = *(const bf16x8*)(wb + (size_t)(colBase + n * 16 + lr) * 160
                                       + kk * 32 + lh * 8);
#pragma unroll
        for (int m = 0; m < 4; ++m)
#pragma unroll
            for (int n = 0; n < 4; ++n)
                acc[m][n] = __builtin_amdgcn_mfma_f32_16x16x32_bf16(
                    a[m], b[n], acc[m][n], 0, 0, 0);
    }

    // C/D layout: col = lane&15, row = (lane>>4)*4 + j   [m89-verified]
    const int group = blockIdx.x * 2 + wn;    // w-group = 64-col slab
#pragma unroll
    for (int m = 0; m < 4; ++m) {
        float mx[4] = {0.f, 0.f, 0.f, 0.f};   // Σ_n max(z,0)      per j
        float pr[4] = {1.f, 1.f, 1.f, 1.f};   // Π_n (1+e^{-|z|})  per j
        float zi[4] = {0.f, 0.f, 0.f, 0.f};   // Σ_n z*im          per j
        const int rowM = rowBase + m * 16 + lh * 4;
#pragma unroll
        for (int n = 0; n < 4; ++n) {
            const int col = colBase + n * 16 + lr;
            const float bias = b2[col];
#pragma unroll
            for (int j = 0; j < 4; ++j) {
                const float z = acc[m][n][j] + bias;
                const float im = images[(size_t)(rowM + j) * 12288 + col];
                mx[j] += fmaxf(z, 0.0f);
                pr[j] *= 1.0f + __expf(-fabsf(z));   // native v_exp_f32
                zi[j] = fmaf(z, im, zi[j]);
            }
        }
        float part[4];
#pragma unroll
        for (int j = 0; j < 4; ++j)
            part[j] = mx[j] + __logf(pr[j]) - zi[j]; // native v_log_f32

        // reduce across the 16 lr lanes (w dimension)
#pragma unroll
        for (int off = 8; off >= 1; off >>= 1)
#pragma unroll
            for (int j = 0; j < 4; ++j)
                part[j] += __shfl_xor(part[j], off, 16);
        if (lr == 0) {
#pragma unroll
            for (int j = 0; j < 4; ++j)
                out[(size_t)(rowM + j) * 192 + group] = part[j];
        }
    }
}

extern "C" void kernel_launch(void* const* d_in, const int* in_sizes, int n_in,
                              void* d_out, int out_size, void* d_ws, size_t ws_size,
                              hipStream_t stream) {
    const float* digits = (const float*)d_in[0];  // [8,512,10]
    const float* styles = (const float*)d_in[1];  // [8,512,50]
    const float* images = (const float*)d_in[2];  // [8,512,3,64,64]
    const float* Wh     = (const float*)d_in[3];  // [60,512]
    const float* bh     = (const float*)d_in[4];  // [512]
    const float* W1     = (const float*)d_in[5];  // [512,160]
    const float* b1     = (const float*)d_in[6];  // [160]
    const float* W2     = (const float*)d_in[7];  // [160,12288]
    const float* b2     = (const float*)d_in[8];  // [12288]
    float* out = (float*)d_out;                   // [4096,192]

    const int R = 4096;

    // workspace (9 MB total): h bf16 [R,512] | t bf16 [R,160] | W2T bf16 [12288,160]
    __hip_bfloat16* h   = (__hip_bfloat16*)d_ws;
    __hip_bfloat16* tt  = h + (size_t)R * 512;
    __hip_bfloat16* w2t = tt + (size_t)R * 160;

    dim3 gridT(384, 5);
    w2_transpose_kernel<<<gridT, 256, 0, stream>>>(W2, w2t);

    dec_hidden_kernel<<<R / 8, 512, 0, stream>>>(digits, styles, Wh, bh, h);
    hidden1_kernel<<<R / 8, 192, 0, stream>>>(h, W1, b1, tt);

    dim3 grid3(96, 32);
    out_loss_mfma_kernel<<<grid3, 256, 0, stream>>>(tt, w2t, b2, images, out);
}

// Round 4
// 106.786 us; speedup vs baseline: 3.5814x; 1.0626x over previous
//
#include <hip/hip_runtime.h>
#include <hip/hip_bf16.h>
#include <math.h>

// Decoder: h = relu(cat @ W_h + b_h); t = selu(h @ W1 + b1);
// x = sigmoid(t @ W2 + b2); loss = sum_w(softplus(z) - z*img)   [== -(BCE log-lik)]
// R = S*B = 4096 rows; Hn=512, bott=160, P=12288 = 192 groups * 64 (w).

#define SELU_SCALE 1.0507009873554804934193349852946f
#define SELU_ALPHA 1.6732632423543772848170429916717f

typedef __attribute__((ext_vector_type(8))) short bf16x8;   // 8 bf16 (4 VGPRs)
typedef __attribute__((ext_vector_type(4))) float f32x4;    // MFMA accumulator

// ---------------- K0: W2T[n][k] = bf16(W2[k][n]) ---------------------------
__global__ __launch_bounds__(256) void w2_transpose_kernel(
    const float* __restrict__ W2,        // [160,12288]
    __hip_bfloat16* __restrict__ W2T)    // [12288,160]
{
    __shared__ float tile[32][33];
    const int nBase = blockIdx.x * 32;
    const int kBase = blockIdx.y * 32;
    const int tx = threadIdx.x & 31;
    const int ty = threadIdx.x >> 5;     // 0..7
#pragma unroll
    for (int i = 0; i < 4; ++i) {
        const int k = kBase + ty + i * 8;
        tile[ty + i * 8][tx] = W2[(size_t)k * 12288 + nBase + tx];
    }
    __syncthreads();
#pragma unroll
    for (int i = 0; i < 4; ++i) {
        const int n = nBase + ty + i * 8;
        W2T[(size_t)n * 160 + kBase + tx] = __float2bfloat16(tile[tx][ty + i * 8]);
    }
}

// ---------------- K1: h[R,512] = bf16(relu(cat @ Wh + bh)) -----------------
__global__ __launch_bounds__(512) void dec_hidden_kernel(
    const float* __restrict__ digits,   // [R,10]
    const float* __restrict__ styles,   // [R,50]
    const float* __restrict__ Wh,       // [60,512]
    const float* __restrict__ bh,       // [512]
    __hip_bfloat16* __restrict__ h)     // [R,512] bf16
{
    __shared__ float cat_s[8][60];
    const int tid = threadIdx.x;
    const int rowBase = blockIdx.x * 8;

    for (int i = tid; i < 8 * 60; i += 512) {
        const int r = i / 60, k = i % 60;
        const int row = rowBase + r;
        cat_s[r][k] = (k < 10) ? digits[row * 10 + k]
                               : styles[row * 50 + (k - 10)];
    }
    __syncthreads();

    float acc[8];
    const float bias = bh[tid];
#pragma unroll
    for (int r = 0; r < 8; ++r) acc[r] = bias;

    for (int k = 0; k < 60; ++k) {
        const float w = Wh[k * 512 + tid];
#pragma unroll
        for (int r = 0; r < 8; ++r) acc[r] = fmaf(cat_s[r][k], w, acc[r]);
    }
#pragma unroll
    for (int r = 0; r < 8; ++r)
        h[(size_t)(rowBase + r) * 512 + tid] = __float2bfloat16(fmaxf(acc[r], 0.0f));
}

// ---------------- K2: t[R,160] = bf16(selu(h @ W1 + b1)) -------------------
__global__ __launch_bounds__(192) void hidden1_kernel(
    const __hip_bfloat16* __restrict__ h,   // [R,512] bf16
    const float* __restrict__ W1,           // [512,160]
    const float* __restrict__ b1,           // [160]
    __hip_bfloat16* __restrict__ t)         // [R,160] bf16
{
    __shared__ float h_s[8 * 512];
    const int tid = threadIdx.x;
    const int rowBase = blockIdx.x * 8;
    const __hip_bfloat16* hsrc = h + (size_t)rowBase * 512;
    for (int i = tid; i < 8 * 512; i += 192) h_s[i] = __bfloat162float(hsrc[i]);
    __syncthreads();

    if (tid < 160) {
        float acc[8];
        const float bias = b1[tid];
#pragma unroll
        for (int r = 0; r < 8; ++r) acc[r] = bias;

        for (int k = 0; k < 512; k += 4) {
            const float w0 = W1[(size_t)(k + 0) * 160 + tid];
            const float w1 = W1[(size_t)(k + 1) * 160 + tid];
            const float w2 = W1[(size_t)(k + 2) * 160 + tid];
            const float w3 = W1[(size_t)(k + 3) * 160 + tid];
#pragma unroll
            for (int r = 0; r < 8; ++r) {
                const float4 hv = *(const float4*)&h_s[r * 512 + k];
                float a = acc[r];
                a = fmaf(hv.x, w0, a);
                a = fmaf(hv.y, w1, a);
                a = fmaf(hv.z, w2, a);
                a = fmaf(hv.w, w3, a);
                acc[r] = a;
            }
        }
#pragma unroll
        for (int r = 0; r < 8; ++r) {
            const float z = acc[r];
            const float s = (z > 0.0f) ? (SELU_SCALE * z)
                                       : (SELU_SCALE * SELU_ALPHA * expm1f(z));
            t[(size_t)(rowBase + r) * 160 + tid] = __float2bfloat16(s);
        }
    }
}

// ---------------- K3: MFMA GEMM (t @ W2) fused with sigmoid-BCE loss -------
// grid (96, 32); block 256 = 4 waves as 2x2; block tile 128x128, wave 64x64.
// Epilogue is software-pipelined: image batch m+1 (16 regs) prefetched while
// computing batch m; batch 0 issued before the MFMA k-loop so its HBM latency
// hides under the GEMM. Native v_exp_f32 + one v_log_f32 per 4 elements.
__global__ __launch_bounds__(256) void out_loss_mfma_kernel(
    const __hip_bfloat16* __restrict__ t,    // [4096,160]
    const __hip_bfloat16* __restrict__ w2t,  // [12288,160]
    const float* __restrict__ b2,            // [12288]
    const float* __restrict__ images,        // [4096,12288]
    float* __restrict__ out)                 // [4096,192]
{
    const int tid = threadIdx.x;
    const int lane = tid & 63;
    const int wv = tid >> 6;
    const int wm = wv >> 1, wn = wv & 1;
    const int rowBase = blockIdx.y * 128 + wm * 64;
    const int colBase = blockIdx.x * 128 + wn * 64;
    const int lr = lane & 15;     // 16-dim index within fragment
    const int lh = lane >> 4;     // k-block / row-group index

    const short* tb = (const short*)t;
    const short* wb = (const short*)w2t;

    // hoisted bias (4 scalar loads, L2-hot)
    float bc[4];
#pragma unroll
    for (int n = 0; n < 4; ++n) bc[n] = b2[colBase + n * 16 + lr];

    // image batch registers: im[parity][n*4+j]; this thread's cols/rows
    const float* imgB = images + colBase + lr;   // + row*12288 + n*16
    float im[2][16];

    // batch 0 (m=0) issued before GEMM -> latency hidden under k-loop
#pragma unroll
    for (int n = 0; n < 4; ++n)
#pragma unroll
        for (int j = 0; j < 4; ++j)
            im[0][n * 4 + j] =
                imgB[(size_t)(rowBase + lh * 4 + j) * 12288 + n * 16];

    f32x4 acc[4][4] = {};

#pragma unroll
    for (int kk = 0; kk < 5; ++kk) {          // K = 160 = 5 * 32
        bf16x8 a[4], b[4];
#pragma unroll
        for (int m = 0; m < 4; ++m)
            a[m] = *(const bf16x8*)(tb + (size_t)(rowBase + m * 16 + lr) * 160
                                       + kk * 32 + lh * 8);
#pragma unroll
        for (int n = 0; n < 4; ++n)
            b[n] = *(const bf16x8*)(wb + (size_t)(colBase + n * 16 + lr) * 160
                                       + kk * 32 + lh * 8);
#pragma unroll
        for (int m = 0; m < 4; ++m)
#pragma unroll
            for (int n = 0; n < 4; ++n)
                acc[m][n] = __builtin_amdgcn_mfma_f32_16x16x32_bf16(
                    a[m], b[n], acc[m][n], 0, 0, 0);
    }

    // C/D layout: col = lane&15, row = (lane>>4)*4 + j   [m89-verified]
    const int group = blockIdx.x * 2 + wn;    // w-group = 64-col slab
#pragma unroll
    for (int m = 0; m < 4; ++m) {             // fully unrolled: im idx const
        // prefetch batch m+1 while computing batch m
        if (m < 3) {
#pragma unroll
            for (int n = 0; n < 4; ++n)
#pragma unroll
                for (int j = 0; j < 4; ++j)
                    im[(m + 1) & 1][n * 4 + j] =
                        imgB[(size_t)(rowBase + (m + 1) * 16 + lh * 4 + j) * 12288
                             + n * 16];
        }

        float mx[4] = {0.f, 0.f, 0.f, 0.f};   // Σ_n max(z,0)      per j
        float pr[4] = {1.f, 1.f, 1.f, 1.f};   // Π_n (1+e^{-|z|})  per j
        float zi[4] = {0.f, 0.f, 0.f, 0.f};   // Σ_n z*im          per j
        const int rowM = rowBase + m * 16 + lh * 4;
#pragma unroll
        for (int n = 0; n < 4; ++n) {
#pragma unroll
            for (int j = 0; j < 4; ++j) {
                const float z = acc[m][n][j] + bc[n];
                const float imv = im[m & 1][n * 4 + j];
                mx[j] += fmaxf(z, 0.0f);
                pr[j] *= 1.0f + __expf(-fabsf(z));   // native v_exp_f32
                zi[j] = fmaf(z, imv, zi[j]);
            }
        }
        float part[4];
#pragma unroll
        for (int j = 0; j < 4; ++j)
            part[j] = mx[j] + __logf(pr[j]) - zi[j]; // native v_log_f32

        // reduce across the 16 lr lanes (w dimension)
#pragma unroll
        for (int off = 8; off >= 1; off >>= 1)
#pragma unroll
            for (int j = 0; j < 4; ++j)
                part[j] += __shfl_xor(part[j], off, 16);
        if (lr == 0) {
#pragma unroll
            for (int j = 0; j < 4; ++j)
                out[(size_t)(rowM + j) * 192 + group] = part[j];
        }
    }
}

extern "C" void kernel_launch(void* const* d_in, const int* in_sizes, int n_in,
                              void* d_out, int out_size, void* d_ws, size_t ws_size,
                              hipStream_t stream) {
    const float* digits = (const float*)d_in[0];  // [8,512,10]
    const float* styles = (const float*)d_in[1];  // [8,512,50]
    const float* images = (const float*)d_in[2];  // [8,512,3,64,64]
    const float* Wh     = (const float*)d_in[3];  // [60,512]
    const float* bh     = (const float*)d_in[4];  // [512]
    const float* W1     = (const float*)d_in[5];  // [512,160]
    const float* b1     = (const float*)d_in[6];  // [160]
    const float* W2     = (const float*)d_in[7];  // [160,12288]
    const float* b2     = (const float*)d_in[8];  // [12288]
    float* out = (float*)d_out;                   // [4096,192]

    const int R = 4096;

    // workspace (9 MB total): h bf16 [R,512] | t bf16 [R,160] | W2T bf16 [12288,160]
    __hip_bfloat16* h   = (__hip_bfloat16*)d_ws;
    __hip_bfloat16* tt  = h + (size_t)R * 512;
    __hip_bfloat16* w2t = tt + (size_t)R * 160;

    dim3 gridT(384, 5);
    w2_transpose_kernel<<<gridT, 256, 0, stream>>>(W2, w2t);

    dec_hidden_kernel<<<R / 8, 512, 0, stream>>>(digits, styles, Wh, bh, h);
    hidden1_kernel<<<R / 8, 192, 0, stream>>>(h, W1, b1, tt);

    dim3 grid3(96, 32);
    out_loss_mfma_kernel<<<grid3, 256, 0, stream>>>(tt, w2t, b2, images, out);
}